// Round 1
// baseline (122.841 us; speedup 1.0000x reference)
//
#include <hip/hip_runtime.h>

#define N_IN   4096
#define N_OUT  4082      // 4096 - 15 + 1
#define KS     15
#define BX     16
#define BY     16
#define RX     4
#define RY     8
#define TILE_W (BX * RX)           // 64
#define TILE_H (BY * RY)           // 128
#define IH     (TILE_H + KS - 1)   // 142 rows staged
#define PITCH  80                  // padded LDS row pitch (words); tile needs 78
#define CPR    (PITCH / 4)         // float4 chunks per LDS row = 20

__global__ __launch_bounds__(256) void Conv2DScratch_82025285419642_kernel(
    const float* __restrict__ x, const float* __restrict__ w,
    const float* __restrict__ bias, float* __restrict__ out)
{
    __shared__ float xs[IH * PITCH];   // 142*80*4 = 45440 B -> 3 blocks/CU

    const int tx  = threadIdx.x;       // 0..15
    const int ty  = threadIdx.y;       // 0..15
    const int tid = ty * BX + tx;
    const int c0  = blockIdx.x * TILE_W;   // output col base
    const int r0  = blockIdx.y * TILE_H;   // output row base

    // ---- stage input tile (global -> LDS), float4 chunks, guarded at edges ----
    for (int c = tid; c < IH * CPR; c += BX * BY) {
        const int row = c / CPR;
        const int cc  = (c - row * CPR) * 4;
        const int gr  = r0 + row;
        const int gc  = c0 + cc;
        float4 v;
        if (gr < N_IN && gc + 3 < N_IN) {
            v = *reinterpret_cast<const float4*>(&x[gr * N_IN + gc]);
        } else {
            v.x = (gr < N_IN && gc + 0 < N_IN) ? x[gr * N_IN + gc + 0] : 0.f;
            v.y = (gr < N_IN && gc + 1 < N_IN) ? x[gr * N_IN + gc + 1] : 0.f;
            v.z = (gr < N_IN && gc + 2 < N_IN) ? x[gr * N_IN + gc + 2] : 0.f;
            v.w = (gr < N_IN && gc + 3 < N_IN) ? x[gr * N_IN + gc + 3] : 0.f;
        }
        *reinterpret_cast<float4*>(&xs[row * PITCH + cc]) = v;
    }
    __syncthreads();

    // ---- register-blocked direct conv: RY x RX outputs per thread ----
    float acc[RY][RX];
    #pragma unroll
    for (int i = 0; i < RY; ++i)
        #pragma unroll
        for (int j = 0; j < RX; ++j) acc[i][j] = 0.f;

    const int rbase = ty * RY;   // LDS row of this thread's first output row
    const int cbase = tx * RX;   // LDS col of this thread's first output col

    for (int r = 0; r < RY + KS - 1; ++r) {      // 22 input rows stream by
        const float* rowp = &xs[(rbase + r) * PITCH + cbase];
        // 18-float strip in registers via vector LDS reads (16B-aligned)
        float s[RX + KS - 1];
        const float4 v0 = *reinterpret_cast<const float4*>(rowp + 0);
        const float4 v1 = *reinterpret_cast<const float4*>(rowp + 4);
        const float4 v2 = *reinterpret_cast<const float4*>(rowp + 8);
        const float4 v3 = *reinterpret_cast<const float4*>(rowp + 12);
        const float2 v4 = *reinterpret_cast<const float2*>(rowp + 16);
        s[0]=v0.x;  s[1]=v0.y;  s[2]=v0.z;  s[3]=v0.w;
        s[4]=v1.x;  s[5]=v1.y;  s[6]=v1.z;  s[7]=v1.w;
        s[8]=v2.x;  s[9]=v2.y;  s[10]=v2.z; s[11]=v2.w;
        s[12]=v3.x; s[13]=v3.y; s[14]=v3.z; s[15]=v3.w;
        s[16]=v4.x; s[17]=v4.y;

        #pragma unroll
        for (int ry = 0; ry < RY; ++ry) {
            const int p = r - ry;              // filter row feeding output row ry
            if (p >= 0 && p < KS) {            // wave-uniform (scalar) branch
                const float* wr = &w[p * KS];  // uniform -> s_load path
                #pragma unroll
                for (int q = 0; q < KS; ++q) {
                    const float wv = wr[q];
                    #pragma unroll
                    for (int rx = 0; rx < RX; ++rx)
                        acc[ry][rx] = fmaf(s[q + rx], wv, acc[ry][rx]);
                }
            }
        }
    }

    // ---- epilogue: bias + guarded stores ----
    const float b0 = bias[0];
    #pragma unroll
    for (int ry = 0; ry < RY; ++ry) {
        const int orow = r0 + rbase + ry;
        if (orow < N_OUT) {
            const long obase = (long)orow * N_OUT + c0 + cbase;
            #pragma unroll
            for (int rx = 0; rx < RX; ++rx) {
                if (c0 + cbase + rx < N_OUT)
                    out[obase + rx] = acc[ry][rx] + b0;
            }
        }
    }
}

extern "C" void kernel_launch(void* const* d_in, const int* in_sizes, int n_in,
                              void* d_out, int out_size, void* d_ws, size_t ws_size,
                              hipStream_t stream) {
    const float* x    = (const float*)d_in[0];
    const float* w    = (const float*)d_in[1];
    const float* bias = (const float*)d_in[2];
    float* out        = (float*)d_out;

    dim3 block(BX, BY);
    dim3 grid((N_OUT + TILE_W - 1) / TILE_W,   // 64
              (N_OUT + TILE_H - 1) / TILE_H);  // 32
    Conv2DScratch_82025285419642_kernel<<<grid, block, 0, stream>>>(x, w, bias, out);
}

// Round 2
// 51.204 us; speedup vs baseline: 2.3991x; 2.3991x over previous
//
#include <hip/hip_runtime.h>

#define N_IN   4096
#define N_OUT  4082      // 4096 - 15 + 1
#define KS     15
#define TM     128       // output rows per block
#define TN     256       // output cols per block
#define PATCH_R 142      // TM + KS - 1
#define PATCH_C 272      // TN + 16 (last 16-col window needs 32 cols)
#define C4      (PATCH_C / 4)          // 68 float4 chunks per patch row
#define PITCH   280      // LDS row pitch in bf16 elems (560 B = 35*16; 140 words % 32 = 12 -> conflict-min)

typedef __attribute__((ext_vector_type(8))) short bf16x8;
typedef __attribute__((ext_vector_type(4))) float f32x4;

__device__ inline unsigned short f2bf(float f) {   // round-to-nearest-even
    unsigned u = __builtin_bit_cast(unsigned, f);
    u += 0x7FFFu + ((u >> 16) & 1u);
    return (unsigned short)(u >> 16);
}

__global__ __launch_bounds__(512, 4) void Conv2DScratch_82025285419642_kernel(
    const float* __restrict__ x, const float* __restrict__ w,
    const float* __restrict__ bias, float* __restrict__ out)
{
    __shared__ unsigned short xs[PATCH_R * PITCH];   // 79,520 B -> 2 blocks/CU

    const int tid  = threadIdx.x;
    const int lane = tid & 63;
    const int wv   = tid >> 6;            // 0..7 : wave owns one 16-row tile band
    const int r0   = blockIdx.y * TM;     // output row base
    const int c0   = blockIdx.x * TN;     // output col base

    // ---- build the 15 constant B fragments: B[(p,q)][n] = w[p][q-n] ----
    // lane: n = lane&15 (output col shift), q = (lane>>4)*8 + e
    const int n = lane & 15;
    const int g = lane >> 4;
    bf16x8 bfrag[KS];
    #pragma unroll
    for (int p = 0; p < KS; ++p) {
        #pragma unroll
        for (int e = 0; e < 8; ++e) {
            const int q   = g * 8 + e;
            const int idx = q - n;                       // filter col
            const float v = (idx >= 0 && idx < KS) ? w[p * KS + idx] : 0.f;
            bfrag[p][e] = (short)f2bf(v);
        }
    }

    // ---- stage x patch fp32 -> bf16 LDS (guarded; 4096 is float4-aligned) ----
    for (int c = tid; c < PATCH_R * C4; c += 512) {
        const int row = c / C4;                // const-div -> magic mul
        const int c4  = c - row * C4;
        const int gr  = r0 + row;
        const int gc  = c0 + c4 * 4;
        float4 v = make_float4(0.f, 0.f, 0.f, 0.f);
        if (gr < N_IN && gc < N_IN)            // chunks are fully in or fully out
            v = *reinterpret_cast<const float4*>(&x[(long)gr * N_IN + gc]);
        ushort4 b;
        b.x = f2bf(v.x); b.y = f2bf(v.y); b.z = f2bf(v.z); b.w = f2bf(v.w);
        *reinterpret_cast<ushort4*>(&xs[row * PITCH + c4 * 4]) = b;
    }
    __syncthreads();

    const float b0 = bias[0];

    // ---- per wave: 16 output tiles of 16x16, 15 MFMAs each ----
    const int arow0 = wv * 16 + (lane & 15);   // A row m = lane&15
    const int acol  = g * 8;                   // A k-elems: q = g*8 + e (matches B build)

    for (int t = 0; t < TN / 16; ++t) {
        f32x4 acc = {0.f, 0.f, 0.f, 0.f};
        const unsigned short* ap = &xs[arow0 * PITCH + t * 16 + acol];
        #pragma unroll
        for (int p = 0; p < KS; ++p) {
            const bf16x8 a = *reinterpret_cast<const bf16x8*>(ap + p * PITCH);
            acc = __builtin_amdgcn_mfma_f32_16x16x32_bf16(a, bfrag[p], acc, 0, 0, 0);
        }
        // D layout (m89): col = lane&15, row = (lane>>4)*4 + r
        const int ocol = c0 + t * 16 + n;
        if (ocol < N_OUT) {
            #pragma unroll
            for (int r = 0; r < 4; ++r) {
                const int orow = r0 + wv * 16 + g * 4 + r;
                if (orow < N_OUT)
                    out[(long)orow * N_OUT + ocol] = acc[r] + b0;
            }
        }
    }
}

extern "C" void kernel_launch(void* const* d_in, const int* in_sizes, int n_in,
                              void* d_out, int out_size, void* d_ws, size_t ws_size,
                              hipStream_t stream) {
    const float* x    = (const float*)d_in[0];
    const float* w    = (const float*)d_in[1];
    const float* bias = (const float*)d_in[2];
    float* out        = (float*)d_out;

    dim3 block(512);
    dim3 grid((N_OUT + TN - 1) / TN,    // 16
              (N_OUT + TM - 1) / TM);   // 32  -> 512 blocks = exactly 2/CU
    Conv2DScratch_82025285419642_kernel<<<grid, block, 0, stream>>>(x, w, bias, out);
}